// Round 7
// baseline (58.262 us; speedup 1.0000x reference)
//
#include <hip/hip_runtime.h>

// Segment-mean over N rows of F=256 f32 features into C=37 classes,
// scattered into queue[C][2][F] at slot tail[c].
//
// k_accum: one row per WAVE via float4 (lane l owns cols [4l,4l+4)), each
// wave has a PRIVATE 37KB LDS class-sum buffer -> no cross-wave races, no
// atomics. 16-row batches, A/B register double-buffer (unrolled x2, no
// copies): 16KB/wave in flight through the RMW phase, half the drain points.
//
// k_tail : merged reduce+finalize (unchanged from R6).

constexpr int C   = 37;
constexpr int F   = 256;
constexpr int WPB = 4;    // waves per block
constexpr int B   = 16;   // rows per batch

__global__ __launch_bounds__(256, 1) void k_accum(
    const float* __restrict__ feat, const int* __restrict__ labels,
    float* __restrict__ psums, float* __restrict__ pcnts, int rpw)
{
    __shared__ float ls[WPB][C * F];     // 4 x 37888 B = 148 KB
    __shared__ int   lcnt[WPB][64];
    const int t = threadIdx.x;
    const int w = t >> 6;
    const int l = t & 63;

    // Each wave zeroes its own buffer (no sync needed before use).
    float4* lz = (float4*)ls[w];
    for (int i = l; i < C * F / 4; i += 64)
        lz[i] = make_float4(0.f, 0.f, 0.f, 0.f);

    const size_t rbase = (size_t)blockIdx.x * (size_t)(rpw * WPB) + (size_t)w * rpw;
    const float4* f4 = (const float4*)feat;      // row r -> f4[r*64 + l]

    int cnt = 0;   // count for class l (meaningful for l < C)

    float4 bufA[B]; int clsA[B];
    float4 bufB[B]; int clsB[B];

    #pragma unroll
    for (int k = 0; k < B; ++k) {                // preload batch A (rows 0..15)
        bufA[k] = f4[(rbase + k) * 64 + l];
        clsA[k] = labels[rbase + k];
    }

    for (int i = 0; i < rpw; i += 2 * B) {
        const bool moreB = (i + B) < rpw;        // wave-uniform
        if (moreB) {
            #pragma unroll
            for (int k = 0; k < B; ++k) {
                bufB[k] = f4[(rbase + i + B + k) * 64 + l];
                clsB[k] = labels[rbase + i + B + k];
            }
        }
        #pragma unroll
        for (int k = 0; k < B; ++k) {            // RMW batch A
            const int c = clsA[k];
            cnt += (c == l);
            float4* p = (float4*)&ls[w][c * F + 4 * l];  // lane-exclusive slot
            float4 a = *p;
            a.x += bufA[k].x; a.y += bufA[k].y; a.z += bufA[k].z; a.w += bufA[k].w;
            *p = a;
        }
        const bool moreA = (i + 2 * B) < rpw;
        if (moreA) {
            #pragma unroll
            for (int k = 0; k < B; ++k) {
                bufA[k] = f4[(rbase + i + 2 * B + k) * 64 + l];
                clsA[k] = labels[rbase + i + 2 * B + k];
            }
        }
        if (moreB) {
            #pragma unroll
            for (int k = 0; k < B; ++k) {        // RMW batch B
                const int c = clsB[k];
                cnt += (c == l);
                float4* p = (float4*)&ls[w][c * F + 4 * l];
                float4 a = *p;
                a.x += bufB[k].x; a.y += bufB[k].y; a.z += bufB[k].z; a.w += bufB[k].w;
                *p = a;
            }
        }
    }

    lcnt[w][l] = cnt;
    __syncthreads();

    float* po = psums + (size_t)blockIdx.x * (C * F);
    for (int i = t; i < C * F; i += 256)
        po[i] = ls[0][i] + ls[1][i] + ls[2][i] + ls[3][i];
    if (t < C)
        pcnts[(size_t)blockIdx.x * C + t] =
            (float)(lcnt[0][t] + lcnt[1][t] + lcnt[2][t] + lcnt[3][t]);
}

__global__ __launch_bounds__(256) void k_tail(
    const float* __restrict__ psums, const float* __restrict__ pcnts,
    const float* __restrict__ queue, const int* __restrict__ tail,
    float* __restrict__ out, int NB)
{
    const int c  = blockIdx.x;          // class
    const int q  = blockIdx.y;          // column quarter (0..3)
    const int t  = threadIdx.x;
    const int cl = t & 63;              // column within quarter
    const int bs = t >> 6;              // b-slice (0..3)
    const int col = q * 64 + cl;
    const int npb = NB >> 2;            // partials per slice

    // 8-way unrolled partial-sum reduction: coalesced 256B per load instr.
    float a0 = 0.f, a1 = 0.f, a2 = 0.f, a3 = 0.f;
    float a4 = 0.f, a5 = 0.f, a6 = 0.f, a7 = 0.f;
    const size_t stride = (size_t)C * F;
    const float* p = psums + (size_t)(bs * npb) * stride + (size_t)c * F + col;
    for (int b = 0; b < npb; b += 8) {
        a0 += p[(size_t)(b + 0) * stride];
        a1 += p[(size_t)(b + 1) * stride];
        a2 += p[(size_t)(b + 2) * stride];
        a3 += p[(size_t)(b + 3) * stride];
        a4 += p[(size_t)(b + 4) * stride];
        a5 += p[(size_t)(b + 5) * stride];
        a6 += p[(size_t)(b + 6) * stride];
        a7 += p[(size_t)(b + 7) * stride];
    }
    const float acc = ((a0 + a1) + (a2 + a3)) + ((a4 + a5) + (a6 + a7));

    __shared__ float reds[256];
    __shared__ float redc[256];
    reds[t] = acc;
    float cnt = 0.f;
    for (int b = t; b < NB; b += 256) cnt += pcnts[(size_t)b * C + c];
    redc[t] = cnt;
    __syncthreads();

    if (t < 64) {
        const float s = ((reds[t] + reds[t + 64]) + (reds[t + 128] + reds[t + 192]));
        float total = 0.f;
        #pragma unroll
        for (int k = 0; k < 4; ++k) total += redc[t + 64 * k];
        // reduce the 64 lanes' count partials via shuffle
        float ctot = total;
        #pragma unroll
        for (int off = 32; off > 0; off >>= 1)
            ctot += __shfl_down(ctot, off, 64);
        ctot = __shfl(ctot, 0, 64);

        const bool  present = ctot > 0.f;
        const float mean    = s / fmaxf(ctot, 1.f);

        int tl = tail[c];
        tl = tl < 0 ? 0 : (tl > 1 ? 1 : tl);

        const float q0 = queue[((size_t)c * 2 + 0) * F + col];
        const float q1 = queue[((size_t)c * 2 + 1) * F + col];
        float o0 = q0, o1 = q1;
        if (tl == 0) o0 = present ? mean : q0;
        else         o1 = present ? mean : q1;
        out[((size_t)c * 2 + 0) * F + col] = o0;
        out[((size_t)c * 2 + 1) * F + col] = o1;
    }
}

extern "C" void kernel_launch(void* const* d_in, const int* in_sizes, int n_in,
                              void* d_out, int out_size, void* d_ws, size_t ws_size,
                              hipStream_t stream)
{
    const float* feat   = (const float*)d_in[0];
    const int*   labels = (const int*)d_in[1];
    const float* queue  = (const float*)d_in[2];
    const int*   tail   = (const int*)d_in[3];
    float* out = (float*)d_out;
    float* ws  = (float*)d_ws;

    const int N = in_sizes[1];   // number of rows

    // NB = number of accum blocks (power of two), sized to fit workspace.
    int NB = 256;
    while (NB > 32) {
        size_t need = ((size_t)NB * C * F + (size_t)NB * C + 64) * sizeof(float);
        if (need <= ws_size) break;
        NB >>= 1;
    }
    const int rpw = N / (NB * WPB);   // rows per wave

    float* psums = ws;
    float* pcnts = psums + (size_t)NB * C * F;

    hipLaunchKernelGGL(k_accum, dim3(NB),   dim3(256), 0, stream,
                       feat, labels, psums, pcnts, rpw);
    hipLaunchKernelGGL(k_tail,  dim3(C, 4), dim3(256), 0, stream,
                       psums, pcnts, queue, tail, out, NB);
}

// Round 8
// 55.669 us; speedup vs baseline: 1.0466x; 1.0466x over previous
//
#include <hip/hip_runtime.h>

// Segment-mean over N rows of F=256 f32 features into C=37 classes,
// scattered into queue[C][2][F] at slot tail[c].
//
// k_accum: one row per WAVE via float4 (lane l owns cols [4l,4l+4)), each
// wave has a PRIVATE 37KB LDS class-sum buffer -> no cross-wave races, no
// atomics. 8-row software pipeline (measured best: R5 nontemporal and R7
// 16-row A/B double-buffer both regressed from this configuration).
//
// k_tail : merged reduce+finalize. Grid (C,4): block (c,q) reduces all NB
// partials for 64 columns (coalesced, 8-way ILP), tree-reduces b-slices and
// counts in LDS, computes mean, scatters into the queue slot.

constexpr int C   = 37;
constexpr int F   = 256;
constexpr int WPB = 4;    // waves per block

__global__ __launch_bounds__(256) void k_accum(
    const float* __restrict__ feat, const int* __restrict__ labels,
    float* __restrict__ psums, float* __restrict__ pcnts, int rpw)
{
    __shared__ float ls[WPB][C * F];     // 4 x 37888 B = 148 KB
    __shared__ int   lcnt[WPB][64];
    const int t = threadIdx.x;
    const int w = t >> 6;
    const int l = t & 63;

    // Each wave zeroes its own buffer (no sync needed before use).
    float4* lz = (float4*)ls[w];
    for (int i = l; i < C * F / 4; i += 64)
        lz[i] = make_float4(0.f, 0.f, 0.f, 0.f);

    const size_t rbase = (size_t)blockIdx.x * (size_t)(rpw * WPB) + (size_t)w * rpw;
    const float4* f4 = (const float4*)feat;      // row r -> f4[r*64 + l]

    int cnt = 0;   // count for class l (meaningful for l < C)

    float4 buf[8]; int cls[8];
    #pragma unroll
    for (int k = 0; k < 8; ++k) {
        buf[k] = f4[(rbase + k) * 64 + l];
        cls[k] = labels[rbase + k];
    }

    for (int i = 0; i < rpw; i += 8) {
        float4 nbuf[8]; int ncls[8];
        const bool more = (i + 8) < rpw;     // wave-uniform branch
        if (more) {
            #pragma unroll
            for (int k = 0; k < 8; ++k) {
                nbuf[k] = f4[(rbase + i + 8 + k) * 64 + l];
                ncls[k] = labels[rbase + i + 8 + k];
            }
        }
        #pragma unroll
        for (int k = 0; k < 8; ++k) {
            const int c = cls[k];
            cnt += (c == l);
            float4* p = (float4*)&ls[w][c * F + 4 * l];  // lane-exclusive slot
            float4 a = *p;
            a.x += buf[k].x; a.y += buf[k].y; a.z += buf[k].z; a.w += buf[k].w;
            *p = a;
        }
        if (more) {
            #pragma unroll
            for (int k = 0; k < 8; ++k) { buf[k] = nbuf[k]; cls[k] = ncls[k]; }
        }
    }

    lcnt[w][l] = cnt;
    __syncthreads();

    float* po = psums + (size_t)blockIdx.x * (C * F);
    for (int i = t; i < C * F; i += 256)
        po[i] = ls[0][i] + ls[1][i] + ls[2][i] + ls[3][i];
    if (t < C)
        pcnts[(size_t)blockIdx.x * C + t] =
            (float)(lcnt[0][t] + lcnt[1][t] + lcnt[2][t] + lcnt[3][t]);
}

__global__ __launch_bounds__(256) void k_tail(
    const float* __restrict__ psums, const float* __restrict__ pcnts,
    const float* __restrict__ queue, const int* __restrict__ tail,
    float* __restrict__ out, int NB)
{
    const int c  = blockIdx.x;          // class
    const int q  = blockIdx.y;          // column quarter (0..3)
    const int t  = threadIdx.x;
    const int cl = t & 63;              // column within quarter
    const int bs = t >> 6;              // b-slice (0..3)
    const int col = q * 64 + cl;
    const int npb = NB >> 2;            // partials per slice

    // 8-way unrolled partial-sum reduction: coalesced 256B per load instr.
    float a0 = 0.f, a1 = 0.f, a2 = 0.f, a3 = 0.f;
    float a4 = 0.f, a5 = 0.f, a6 = 0.f, a7 = 0.f;
    const size_t stride = (size_t)C * F;
    const float* p = psums + (size_t)(bs * npb) * stride + (size_t)c * F + col;
    for (int b = 0; b < npb; b += 8) {
        a0 += p[(size_t)(b + 0) * stride];
        a1 += p[(size_t)(b + 1) * stride];
        a2 += p[(size_t)(b + 2) * stride];
        a3 += p[(size_t)(b + 3) * stride];
        a4 += p[(size_t)(b + 4) * stride];
        a5 += p[(size_t)(b + 5) * stride];
        a6 += p[(size_t)(b + 6) * stride];
        a7 += p[(size_t)(b + 7) * stride];
    }
    const float acc = ((a0 + a1) + (a2 + a3)) + ((a4 + a5) + (a6 + a7));

    __shared__ float reds[256];
    __shared__ float redc[256];
    reds[t] = acc;
    float cnt = 0.f;
    for (int b = t; b < NB; b += 256) cnt += pcnts[(size_t)b * C + c];
    redc[t] = cnt;
    __syncthreads();

    if (t < 64) {
        const float s = ((reds[t] + reds[t + 64]) + (reds[t + 128] + reds[t + 192]));
        float total = 0.f;
        #pragma unroll
        for (int k = 0; k < 4; ++k) total += redc[t + 64 * k];
        // reduce the 64 lanes' count partials via shuffle
        float ctot = total;
        #pragma unroll
        for (int off = 32; off > 0; off >>= 1)
            ctot += __shfl_down(ctot, off, 64);
        ctot = __shfl(ctot, 0, 64);

        const bool  present = ctot > 0.f;
        const float mean    = s / fmaxf(ctot, 1.f);

        int tl = tail[c];
        tl = tl < 0 ? 0 : (tl > 1 ? 1 : tl);

        const float q0 = queue[((size_t)c * 2 + 0) * F + col];
        const float q1 = queue[((size_t)c * 2 + 1) * F + col];
        float o0 = q0, o1 = q1;
        if (tl == 0) o0 = present ? mean : q0;
        else         o1 = present ? mean : q1;
        out[((size_t)c * 2 + 0) * F + col] = o0;
        out[((size_t)c * 2 + 1) * F + col] = o1;
    }
}

extern "C" void kernel_launch(void* const* d_in, const int* in_sizes, int n_in,
                              void* d_out, int out_size, void* d_ws, size_t ws_size,
                              hipStream_t stream)
{
    const float* feat   = (const float*)d_in[0];
    const int*   labels = (const int*)d_in[1];
    const float* queue  = (const float*)d_in[2];
    const int*   tail   = (const int*)d_in[3];
    float* out = (float*)d_out;
    float* ws  = (float*)d_ws;

    const int N = in_sizes[1];   // number of rows

    // NB = number of accum blocks (power of two), sized to fit workspace.
    int NB = 256;
    while (NB > 32) {
        size_t need = ((size_t)NB * C * F + (size_t)NB * C + 64) * sizeof(float);
        if (need <= ws_size) break;
        NB >>= 1;
    }
    const int rpw = N / (NB * WPB);   // rows per wave

    float* psums = ws;
    float* pcnts = psums + (size_t)NB * C * F;

    hipLaunchKernelGGL(k_accum, dim3(NB),   dim3(256), 0, stream,
                       feat, labels, psums, pcnts, rpw);
    hipLaunchKernelGGL(k_tail,  dim3(C, 4), dim3(256), 0, stream,
                       psums, pcnts, queue, tail, out, NB);
}